// Round 11
// baseline (374.821 us; speedup 1.0000x reference)
//
#include <hip/hip_runtime.h>
#include <hip/hip_bf16.h>

#define IN_DIM 1024
#define HID 128
#define LAT 64
#define DEGPAD 128

typedef __attribute__((ext_vector_type(8))) short bf16x8;
typedef __attribute__((ext_vector_type(4))) short bf16x4;
typedef __attribute__((ext_vector_type(4))) float f32x4;

// weight-transpose-split arena offsets (bf16 elements)
#define W1T_OFF 0
#define W2T_OFF 131072
#define Wa1T_OFF 139264
#define Wa2T_OFF 147456
#define WsT_OFF 278528
#define WT_TOTAL 282624

__device__ __forceinline__ void splitf(float v, __hip_bfloat16& h, __hip_bfloat16& l) {
    h = __float2bfloat16(v);
    l = __float2bfloat16(v - __bfloat162float(h));
}

// ---------- dense GEMM tile (block tile 128x64, 4 waves 2x2, wave tile 64x32) ----------

template<int AMODE, bool BIAS, bool RELU, bool DIS, bool SPLITOUT, bool NT>
__device__ void dev_gemm(float* smem, int bx, int byy,
        const __hip_bfloat16* __restrict__ Ahi, const __hip_bfloat16* __restrict__ Alo,
        const float* __restrict__ Af,
        const __hip_bfloat16* __restrict__ Bthi, const __hip_bfloat16* __restrict__ Btlo,
        const float* __restrict__ bias, const int* __restrict__ cursor,
        float* __restrict__ Cf, __hip_bfloat16* __restrict__ Chi, __hip_bfloat16* __restrict__ Clo,
        int M, int K, int ldc) {
    int tid = threadIdx.x;
    int w = tid >> 6, lane = tid & 63;
    int wr = w >> 1, wc = w & 1;
    int m0 = byy * 128, n0 = bx * 64;
    int lrow = lane & 15, lk = (lane >> 4) * 8;

    int arow[4];
    size_t aoff[4];
#pragma unroll
    for (int mi = 0; mi < 4; ++mi) {
        arow[mi] = m0 + wr * 64 + mi * 16 + lrow;
        aoff[mi] = (size_t)arow[mi] * K + lk;
    }
    size_t boff[2];
#pragma unroll
    for (int nj = 0; nj < 2; ++nj)
        boff[nj] = (size_t)(n0 + wc * 32 + nj * 16 + lrow) * K + lk;

    f32x4 acc[4][2] = {};

    for (int k0 = 0; k0 < K; k0 += 32) {
        bf16x8 bh[2], bl[2], ah[4], al[4];
#pragma unroll
        for (int nj = 0; nj < 2; ++nj) {
            bh[nj] = *(const bf16x8*)(Bthi + boff[nj] + k0);
            bl[nj] = *(const bf16x8*)(Btlo + boff[nj] + k0);
        }
        if constexpr (AMODE == 0) {
#pragma unroll
            for (int mi = 0; mi < 4; ++mi) {
                ah[mi] = *(const bf16x8*)(Ahi + aoff[mi] + k0);
                al[mi] = *(const bf16x8*)(Alo + aoff[mi] + k0);
            }
        } else {
#pragma unroll
            for (int mi = 0; mi < 4; ++mi) {
                float4 f0 = make_float4(0.f, 0.f, 0.f, 0.f), f1 = f0;
                if (arow[mi] < M) {
                    f0 = *(const float4*)(Af + aoff[mi] + k0);
                    f1 = *(const float4*)(Af + aoff[mi] + k0 + 4);
                }
                float ff[8] = {f0.x, f0.y, f0.z, f0.w, f1.x, f1.y, f1.z, f1.w};
                __attribute__((aligned(16))) __hip_bfloat16 hb[8], lb[8];
#pragma unroll
                for (int t = 0; t < 8; ++t) splitf(ff[t], hb[t], lb[t]);
                ah[mi] = *(const bf16x8*)hb;
                al[mi] = *(const bf16x8*)lb;
            }
        }
#pragma unroll
        for (int mi = 0; mi < 4; ++mi)
#pragma unroll
            for (int nj = 0; nj < 2; ++nj) {
                acc[mi][nj] = __builtin_amdgcn_mfma_f32_16x16x32_bf16(ah[mi], bh[nj], acc[mi][nj], 0, 0, 0);
                acc[mi][nj] = __builtin_amdgcn_mfma_f32_16x16x32_bf16(ah[mi], bl[nj], acc[mi][nj], 0, 0, 0);
                acc[mi][nj] = __builtin_amdgcn_mfma_f32_16x16x32_bf16(al[mi], bh[nj], acc[mi][nj], 0, 0, 0);
            }
    }

    // stage to LDS, stride 68 (2-way banks on stage and read — free)
    int r0 = (lane >> 4) * 4;
#pragma unroll
    for (int mi = 0; mi < 4; ++mi)
#pragma unroll
        for (int nj = 0; nj < 2; ++nj) {
            int cl = wc * 32 + nj * 16 + lrow;
#pragma unroll
            for (int r = 0; r < 4; ++r) {
                int rl = wr * 64 + mi * 16 + r0 + r;
                smem[rl * 68 + cl] = acc[mi][nj][r];
            }
        }
    __syncthreads();

#pragma unroll
    for (int it = 0; it < 8; ++it) {
        int rl = it * 16 + (tid >> 4);
        int c4 = tid & 15;
        int row = m0 + rl;
        if (row < M) {
            int col = n0 + c4 * 4;
            float4 v = *(const float4*)&smem[rl * 68 + c4 * 4];
            if (BIAS) {
                float4 b = *(const float4*)&bias[col];
                v.x += b.x; v.y += b.y; v.z += b.z; v.w += b.w;
            }
            if (RELU) {
                v.x = fmaxf(v.x, 0.f); v.y = fmaxf(v.y, 0.f);
                v.z = fmaxf(v.z, 0.f); v.w = fmaxf(v.w, 0.f);
            }
            if (DIS) {
                float di = rsqrtf((float)(cursor[row] + 1));
                v.x *= di; v.y *= di; v.z *= di; v.w *= di;
            }
            if constexpr (SPLITOUT) {
                float vv[4] = {v.x, v.y, v.z, v.w};
                __attribute__((aligned(8))) __hip_bfloat16 hs[4], ls[4];
#pragma unroll
                for (int k = 0; k < 4; ++k) splitf(vv[k], hs[k], ls[k]);
                *(bf16x4*)&Chi[(size_t)row * ldc + col] = *(bf16x4*)hs;
                *(bf16x4*)&Clo[(size_t)row * ldc + col] = *(bf16x4*)ls;
            } else if constexpr (NT) {
                __builtin_nontemporal_store(*(const f32x4*)&v, (f32x4*)&Cf[(size_t)row * ldc + col]);
            } else {
                *(float4*)&Cf[(size_t)row * ldc + col] = v;
            }
        }
    }
    __syncthreads();
}

// ---------- sst 128x128 tile, upper triangle; mirror written DIRECT from acc ----------

__device__ void dev_sst(float* smem, int bi, int bj,
                        const __hip_bfloat16* __restrict__ Shi, const __hip_bfloat16* __restrict__ Slo,
                        float* __restrict__ C, int M) {
    int tid = threadIdx.x;
    int w = tid >> 6, lane = tid & 63;
    int wr = w >> 1, wc = w & 1;
    int i0 = bi * 128 + wr * 64;
    int j0 = bj * 128 + wc * 64;
    int lrow = lane & 15, lk = (lane >> 4) * 8;

    f32x4 acc[4][4] = {};
#pragma unroll
    for (int ks = 0; ks < 2; ++ks) {
        bf16x8 ah[4], al[4], bh[4], bl[4];
#pragma unroll
        for (int mi = 0; mi < 4; ++mi) {
            size_t off = (size_t)(i0 + mi * 16 + lrow) * 64 + ks * 32 + lk;
            ah[mi] = *(const bf16x8*)(Shi + off);
            al[mi] = *(const bf16x8*)(Slo + off);
        }
#pragma unroll
        for (int nj = 0; nj < 4; ++nj) {
            size_t off = (size_t)(j0 + nj * 16 + lrow) * 64 + ks * 32 + lk;
            bh[nj] = *(const bf16x8*)(Shi + off);
            bl[nj] = *(const bf16x8*)(Slo + off);
        }
#pragma unroll
        for (int mi = 0; mi < 4; ++mi)
#pragma unroll
            for (int nj = 0; nj < 4; ++nj) {
                acc[mi][nj] = __builtin_amdgcn_mfma_f32_16x16x32_bf16(ah[mi], bh[nj], acc[mi][nj], 0, 0, 0);
                acc[mi][nj] = __builtin_amdgcn_mfma_f32_16x16x32_bf16(ah[mi], bl[nj], acc[mi][nj], 0, 0, 0);
                acc[mi][nj] = __builtin_amdgcn_mfma_f32_16x16x32_bf16(al[mi], bh[nj], acc[mi][nj], 0, 0, 0);
            }
    }

    int r0 = (lane >> 4) * 4;

    if (bi != bj) {
#pragma unroll
        for (int mi = 0; mi < 4; ++mi)
#pragma unroll
            for (int nj = 0; nj < 4; ++nj) {
                int orow = j0 + nj * 16 + lrow;
                int ocol = i0 + mi * 16 + r0;
                if (orow < M && ocol < M) {
                    f32x4 v = acc[mi][nj];
                    __builtin_nontemporal_store(v, (f32x4*)&C[(size_t)orow * M + ocol]);
                }
            }
    }

    // normal write via LDS transpose, two 64-col passes (34KB)
#pragma unroll
    for (int p = 0; p < 2; ++p) {
        if (wc == p) {
#pragma unroll
            for (int mi = 0; mi < 4; ++mi)
#pragma unroll
                for (int nj = 0; nj < 4; ++nj) {
                    int cl = nj * 16 + lrow;
#pragma unroll
                    for (int r = 0; r < 4; ++r) {
                        int rl = wr * 64 + mi * 16 + r0 + r;
                        smem[rl * 68 + cl] = acc[mi][nj][r];
                    }
                }
        }
        __syncthreads();
#pragma unroll
        for (int it = 0; it < 8; ++it) {
            int rl = it * 16 + (tid >> 4);
            int c4 = tid & 15;
            int row = bi * 128 + rl;
            int col = bj * 128 + p * 64 + c4 * 4;
            if (row < M && col < M) {
                float4 v = *(const float4*)&smem[rl * 68 + c4 * 4];
                __builtin_nontemporal_store(*(const f32x4*)&v, (f32x4*)&C[(size_t)row * M + col]);
            }
        }
        __syncthreads();
    }
}

// ---------- F=128 SpMM body: lane owns cols 2l,2l+1 (float2 gathers, bit-identical sums) ----------

template<bool BIAS, bool RELU, int OMODE>   // OMODE 0: fp32; 1: split bf16
__device__ __forceinline__ void dev_spmm128(int i, int lane,
        const float* __restrict__ Hin, const int* __restrict__ colPad,
        const int* __restrict__ cursor, const float* __restrict__ bias,
        float* __restrict__ out,
        __hip_bfloat16* __restrict__ ohi, __hip_bfloat16* __restrict__ olo, int n) {
    if (i >= n) return;
    int d = cursor[i];
    float di = rsqrtf((float)(d + 1));
    if (d > DEGPAD) d = DEGPAD;
    const int* cp = colPad + (size_t)i * DEGPAD;
    float2 acc = ((const float2*)(Hin + (size_t)i * 128))[lane];

    int p = 0;
    for (; p + 8 <= d; p += 8) {
        int4 ca = *(const int4*)(cp + p);
        int4 cb = *(const int4*)(cp + p + 4);
        int cc[8] = {ca.x, ca.y, ca.z, ca.w, cb.x, cb.y, cb.z, cb.w};
        float2 v[8];
#pragma unroll
        for (int q = 0; q < 8; ++q)
            v[q] = ((const float2*)(Hin + (size_t)cc[q] * 128))[lane];
#pragma unroll
        for (int q = 0; q < 8; ++q) { acc.x += v[q].x; acc.y += v[q].y; }
    }
    for (; p + 4 <= d; p += 4) {
        int4 ca = *(const int4*)(cp + p);
        int cc[4] = {ca.x, ca.y, ca.z, ca.w};
        float2 v[4];
#pragma unroll
        for (int q = 0; q < 4; ++q)
            v[q] = ((const float2*)(Hin + (size_t)cc[q] * 128))[lane];
#pragma unroll
        for (int q = 0; q < 4; ++q) { acc.x += v[q].x; acc.y += v[q].y; }
    }
    for (; p < d; ++p) {
        float2 v = ((const float2*)(Hin + (size_t)cp[p] * 128))[lane];
        acc.x += v.x; acc.y += v.y;
    }

    float rx = acc.x * di, ry = acc.y * di;
    if (BIAS) {
        float2 b = ((const float2*)bias)[lane];
        rx += b.x; ry += b.y;
    }
    if (RELU) { rx = fmaxf(rx, 0.f); ry = fmaxf(ry, 0.f); }
    size_t base = (size_t)i * 128 + 2 * lane;
    if constexpr (OMODE == 1) {
        __hip_bfloat16 h0, l0, h1, l1;
        splitf(rx, h0, l0);
        splitf(ry, h1, l1);
        union { __hip_bfloat16 b[2]; unsigned u; } uh, ul;
        uh.b[0] = h0; uh.b[1] = h1;
        ul.b[0] = l0; ul.b[1] = l1;
        *(unsigned*)&ohi[base] = uh.u;
        *(unsigned*)&olo[base] = ul.u;
    } else {
        *(float2*)&out[base] = make_float2(rx, ry);
    }
}

template<bool BIAS, bool RELU, int OMODE>
__global__ __launch_bounds__(256) void k_spmm128(const float* __restrict__ Hin,
                                                 const int* __restrict__ colPad,
                                                 const int* __restrict__ cursor,
                                                 const float* __restrict__ bias,
                                                 float* __restrict__ out,
                                                 __hip_bfloat16* __restrict__ ohi,
                                                 __hip_bfloat16* __restrict__ olo, int n) {
    int i = (blockIdx.x * 256 + threadIdx.x) >> 6;
    dev_spmm128<BIAS, RELU, OMODE>(i, threadIdx.x & 63, Hin, colPad, cursor, bias, out, ohi, olo, n);
}

// ---------- F=64 SpMM (8-deep ILP). OMODE 0: fp32; 1: split bf16; 2: fp32 + prescaled copy ----------

template<bool BIAS, bool RELU, int OMODE>
__global__ __launch_bounds__(256) void k_spmm64(const float* __restrict__ Hin,
                                                const int* __restrict__ colPad,
                                                const int* __restrict__ cursor,
                                                const float* __restrict__ bias,
                                                float* __restrict__ out, float* __restrict__ out2,
                                                __hip_bfloat16* __restrict__ ohi,
                                                __hip_bfloat16* __restrict__ olo, int n) {
    int i = (blockIdx.x * 256 + threadIdx.x) >> 6;
    int lane = threadIdx.x & 63;
    if (i >= n) return;
    int d = cursor[i];
    float di = rsqrtf((float)(d + 1));
    if (d > DEGPAD) d = DEGPAD;
    const int* cp = colPad + (size_t)i * DEGPAD;
    float acc = Hin[(size_t)i * 64 + lane];

    int p = 0;
    for (; p + 8 <= d; p += 8) {
        int4 ca = *(const int4*)(cp + p);
        int4 cb = *(const int4*)(cp + p + 4);
        int cc[8] = {ca.x, ca.y, ca.z, ca.w, cb.x, cb.y, cb.z, cb.w};
        float v[8];
#pragma unroll
        for (int q = 0; q < 8; ++q) v[q] = Hin[(size_t)cc[q] * 64 + lane];
#pragma unroll
        for (int q = 0; q < 8; ++q) acc += v[q];
    }
    for (; p + 4 <= d; p += 4) {
        int4 ca = *(const int4*)(cp + p);
        int cc[4] = {ca.x, ca.y, ca.z, ca.w};
        float v[4];
#pragma unroll
        for (int q = 0; q < 4; ++q) v[q] = Hin[(size_t)cc[q] * 64 + lane];
#pragma unroll
        for (int q = 0; q < 4; ++q) acc += v[q];
    }
    for (; p < d; ++p) acc += Hin[(size_t)cp[p] * 64 + lane];

    float r = acc * di;
    if (BIAS) r += bias[lane];
    if (RELU) r = fmaxf(r, 0.f);
    size_t idx = (size_t)i * 64 + lane;
    if constexpr (OMODE == 1) {
        __hip_bfloat16 h, l;
        splitf(r, h, l);
        ohi[idx] = h; olo[idx] = l;
    } else {
        out[idx] = r;
        if constexpr (OMODE == 2) out2[idx] = r * di;
    }
}

// ---------- kernels ----------

__global__ __launch_bounds__(256) void k_prep(const float* __restrict__ W1, const float* __restrict__ W2,
                                              const float* __restrict__ Wa1, const float* __restrict__ Wa2,
                                              const float* __restrict__ Ws,
                                              __hip_bfloat16* __restrict__ hi, __hip_bfloat16* __restrict__ lo,
                                              const int* __restrict__ ei, int* cursor,
                                              int* __restrict__ colPad, int E) {
    int gtid = blockIdx.x * 256 + threadIdx.x;
    int gsz = gridDim.x * 256;
    for (int e = gtid; e < E; e += gsz) {
        int s = ei[e], r = ei[E + e];
        int slot = atomicAdd(&cursor[r], 1);
        if (slot < DEGPAD) colPad[(size_t)r * DEGPAD + slot] = s;
    }
    for (int idx = gtid; idx < WT_TOTAL; idx += gsz) {
        const float* src; int base, shK, Nc;
        if (idx < W2T_OFF)       { src = W1;  base = W1T_OFF;  shK = 10; Nc = 128; }
        else if (idx < Wa1T_OFF) { src = W2;  base = W2T_OFF;  shK = 7;  Nc = 64; }
        else if (idx < Wa2T_OFF) { src = Wa1; base = Wa1T_OFF; shK = 6;  Nc = 128; }
        else if (idx < WsT_OFF)  { src = Wa2; base = Wa2T_OFF; shK = 7;  Nc = 1024; }
        else                     { src = Ws;  base = WsT_OFF;  shK = 6;  Nc = 64; }
        int local = idx - base;
        int nn = local >> shK;
        int k = local & ((1 << shK) - 1);
        splitf(src[(size_t)k * Nc + nn], hi[idx], lo[idx]);
    }
}

__global__ __launch_bounds__(256) void k_g1(const float* __restrict__ x,
                                            const __hip_bfloat16* __restrict__ Whi,
                                            const __hip_bfloat16* __restrict__ Wlo,
                                            const int* __restrict__ cursor,
                                            float* __restrict__ t128, int M) {
    __shared__ float smem[128 * 68];
    int t = blockIdx.x;
    dev_gemm<1, false, false, true, false, false>(smem, t & 1, t >> 1,
        nullptr, nullptr, x, Whi + W1T_OFF, Wlo + W1T_OFF, nullptr, cursor,
        t128, nullptr, nullptr, M, 1024, 128);
}

__global__ __launch_bounds__(256) void k_g2(const __hip_bfloat16* __restrict__ Hhi,
                                            const __hip_bfloat16* __restrict__ Hlo,
                                            const __hip_bfloat16* __restrict__ Whi,
                                            const __hip_bfloat16* __restrict__ Wlo,
                                            const int* __restrict__ cursor,
                                            float* __restrict__ t64, int M) {
    __shared__ float smem[128 * 68];
    dev_gemm<0, false, false, true, false, false>(smem, 0, blockIdx.x,
        Hhi, Hlo, nullptr, Whi + W2T_OFF, Wlo + W2T_OFF, nullptr, cursor,
        t64, nullptr, nullptr, M, 128, 64);
}

__global__ __launch_bounds__(256) void k_g34(const __hip_bfloat16* __restrict__ AZhi,
                                             const __hip_bfloat16* __restrict__ AZlo,
                                             const __hip_bfloat16* __restrict__ Whi,
                                             const __hip_bfloat16* __restrict__ Wlo,
                                             const float* __restrict__ ba1, const float* __restrict__ bs,
                                             const int* __restrict__ cursor,
                                             float* __restrict__ t128,
                                             __hip_bfloat16* __restrict__ Shi, __hip_bfloat16* __restrict__ Slo,
                                             int M, int Mpad) {
    __shared__ float smem[128 * 68];
    int nt2 = (Mpad / 128) * 2;
    int t = blockIdx.x;
    if (t < nt2)
        dev_gemm<0, true, true, true, false, false>(smem, t & 1, t >> 1,
            AZhi, AZlo, nullptr, Whi + Wa1T_OFF, Wlo + Wa1T_OFF, ba1, cursor,
            t128, nullptr, nullptr, M, 64, 128);
    else
        dev_gemm<0, true, true, false, true, false>(smem, 0, t - nt2,
            AZhi, AZlo, nullptr, Whi + WsT_OFF, Wlo + WsT_OFF, bs, nullptr,
            nullptr, Shi, Slo, M, 64, 64);
}

// kernel B: spmm4 (AA = prop(t128) -> split) in parallel with sst tiles [0, sstN)
__global__ __launch_bounds__(256) void k_sp4sst(const float* __restrict__ t128,
                                                const int* __restrict__ colPad,
                                                const int* __restrict__ cursor,
                                                __hip_bfloat16* __restrict__ AAhi,
                                                __hip_bfloat16* __restrict__ AAlo,
                                                const __hip_bfloat16* __restrict__ Shi,
                                                const __hip_bfloat16* __restrict__ Slo,
                                                float* __restrict__ st,
                                                int M, int Mpad, int nsp, int sstN) {
    __shared__ float smem[128 * 68];
    int t = blockIdx.x;
    if (t < nsp) {
        int i = (t * 256 + threadIdx.x) >> 6;
        dev_spmm128<false, false, 1>(i, threadIdx.x & 63, t128, colPad, cursor,
                                     nullptr, nullptr, AAhi, AAlo, M);
    } else {
        int s = t - nsp;               // global sst index in [0, sstN)
        int nt = Mpad / 128;
        int bi = 0;
        while (s >= nt - bi) { s -= nt - bi; bi++; }
        dev_sst(smem, bi, bi + s, Shi, Slo, st, M);
    }
}

// kernel C: G5 (attr = relu(AA@Wa2+ba2), NT) in parallel with sst tiles [sstBase, Tri)
__global__ __launch_bounds__(256) void k_g5sst(const __hip_bfloat16* __restrict__ AAhi,
                                               const __hip_bfloat16* __restrict__ AAlo,
                                               const __hip_bfloat16* __restrict__ Whi,
                                               const __hip_bfloat16* __restrict__ Wlo,
                                               const float* __restrict__ ba2,
                                               const __hip_bfloat16* __restrict__ Shi,
                                               const __hip_bfloat16* __restrict__ Slo,
                                               float* __restrict__ attr, float* __restrict__ st,
                                               int M, int Mpad, int sstBase) {
    __shared__ float smem[128 * 68];
    int nt = Mpad / 128;
    int nG5 = 16 * nt;
    int t = blockIdx.x;
    if (t < nG5) {
        dev_gemm<0, true, true, false, false, true>(smem, t & 15, t >> 4,
            AAhi, AAlo, nullptr, Whi + Wa2T_OFF, Wlo + Wa2T_OFF, ba2, nullptr,
            attr, nullptr, nullptr, M, 128, 1024);
    } else {
        int s = sstBase + (t - nG5);
        int bi = 0;
        while (s >= nt - bi) { s -= nt - bi; bi++; }
        dev_sst(smem, bi, bi + s, Shi, Slo, st, M);
    }
}

// ---------- launch ----------

extern "C" void kernel_launch(void* const* d_in, const int* in_sizes, int n_in,
                              void* d_out, int out_size, void* d_ws, size_t ws_size,
                              hipStream_t stream) {
    const float* x   = (const float*)d_in[0];
    const int*   ei  = (const int*)d_in[1];
    const float* W1  = (const float*)d_in[2];
    const float* b1  = (const float*)d_in[3];
    const float* W2  = (const float*)d_in[4];
    const float* b2  = (const float*)d_in[5];
    const float* Wa1 = (const float*)d_in[6];
    const float* ba1 = (const float*)d_in[7];
    const float* Wa2 = (const float*)d_in[8];
    const float* ba2 = (const float*)d_in[9];
    const float* Ws  = (const float*)d_in[10];
    const float* bs  = (const float*)d_in[11];

    int N = in_sizes[0] / IN_DIM;
    int E = in_sizes[1] / 2;
    int Mpad = ((N + 127) / 128) * 128;
    int nt = Mpad / 128;
    int Tri = nt * (nt + 1) / 2;
    int sstC = Tri < 640 ? Tri : 640;      // sst tiles co-scheduled with G5
    int sstB = Tri - sstC;                 // sst tiles co-scheduled with spmm4

    float* out  = (float*)d_out;
    float* attr = out;
    float* st   = out + (size_t)N * IN_DIM;
    float* zout = st + (size_t)N * N;

    char* basep = (char*)d_ws;
    size_t off = 0;
    auto alloc = [&](size_t bytes) -> void* {
        void* p = basep + off;
        off = (off + bytes + 255) & ~(size_t)255;
        return p;
    };
    int*   colPad = (int*)alloc((size_t)N * DEGPAD * 4);
    int*   cursor = (int*)alloc((size_t)N * 4);
    __hip_bfloat16* Whi = (__hip_bfloat16*)alloc((size_t)WT_TOTAL * 2);
    __hip_bfloat16* Wlo = (__hip_bfloat16*)alloc((size_t)WT_TOTAL * 2);
    float* t128 = (float*)alloc((size_t)N * 128 * 4);
    float* t64  = (float*)alloc((size_t)N * 64 * 4);
    float* zp   = (float*)alloc((size_t)N * 64 * 4);
    __hip_bfloat16* Hhi  = (__hip_bfloat16*)alloc((size_t)Mpad * 128 * 2);
    __hip_bfloat16* Hlo  = (__hip_bfloat16*)alloc((size_t)Mpad * 128 * 2);
    __hip_bfloat16* AZhi = (__hip_bfloat16*)alloc((size_t)Mpad * 64 * 2);
    __hip_bfloat16* AZlo = (__hip_bfloat16*)alloc((size_t)Mpad * 64 * 2);
    __hip_bfloat16* AAhi = (__hip_bfloat16*)alloc((size_t)Mpad * 128 * 2);
    __hip_bfloat16* AAlo = (__hip_bfloat16*)alloc((size_t)Mpad * 128 * 2);
    __hip_bfloat16* Shi  = (__hip_bfloat16*)alloc((size_t)Mpad * 64 * 2);
    __hip_bfloat16* Slo  = (__hip_bfloat16*)alloc((size_t)Mpad * 64 * 2);

    dim3 b256(256);
    int spmm_grid = (N * 64 + 255) / 256;

    // 0. zero cursor
    hipMemsetAsync(cursor, 0, (size_t)N * 4, stream);
    // 1. prep: weight split + edge fill
    k_prep<<<dim3(1280), b256, 0, stream>>>(W1, W2, Wa1, Wa2, Ws, Whi, Wlo, ei, cursor, colPad, E);
    // 2. G1: t128 = dis ⊙ (x @ W1)
    k_g1<<<dim3(2 * nt), b256, 0, stream>>>(x, Whi, Wlo, cursor, t128, N);
    // 3. spmm1: H = relu(dis ⊙ Σ + b1) -> split (float2 gathers)
    k_spmm128<true, true, 1><<<dim3(spmm_grid), b256, 0, stream>>>(
        t128, colPad, cursor, b1, nullptr, Hhi, Hlo, N);
    // 4. G2: t64 = dis ⊙ (H @ W2)
    k_g2<<<dim3(nt), b256, 0, stream>>>(Hhi, Hlo, Whi, Wlo, cursor, t64, N);
    // 5. spmm2: z -> zout (fp32) and zp = dis ⊙ z
    k_spmm64<true, true, 2><<<dim3(spmm_grid), b256, 0, stream>>>(
        t64, colPad, cursor, b2, zout, zp, nullptr, nullptr, N);
    // 6. spmm3: AZ = prop(zp) -> split
    k_spmm64<false, false, 1><<<dim3(spmm_grid), b256, 0, stream>>>(
        zp, colPad, cursor, nullptr, nullptr, nullptr, AZhi, AZlo, N);
    // 7. G3 + G4
    k_g34<<<dim3(3 * nt), b256, 0, stream>>>(AZhi, AZlo, Whi, Wlo, ba1, bs, cursor, t128, Shi, Slo, N, Mpad);
    // 8. kernel B: spmm4 ∥ sst tiles [0, sstB)
    k_sp4sst<<<dim3(spmm_grid + sstB), b256, 0, stream>>>(
        t128, colPad, cursor, AAhi, AAlo, Shi, Slo, st, N, Mpad, spmm_grid, sstB);
    // 9. kernel C: G5 ∥ sst tiles [sstB, Tri)
    k_g5sst<<<dim3(16 * nt + sstC), b256, 0, stream>>>(
        AAhi, AAlo, Whi, Wlo, ba2, Shi, Slo, attr, st, N, Mpad, sstB);
}

// Round 12
// 299.953 us; speedup vs baseline: 1.2496x; 1.2496x over previous
//
#include <hip/hip_runtime.h>
#include <hip/hip_bf16.h>

#define IN_DIM 1024
#define HID 128
#define LAT 64
#define DEGPAD 128

typedef __attribute__((ext_vector_type(8))) short bf16x8;
typedef __attribute__((ext_vector_type(4))) short bf16x4;
typedef __attribute__((ext_vector_type(4))) float f32x4;

// weight-transpose-split arena offsets (bf16 elements)
#define W1T_OFF 0
#define W2T_OFF 131072
#define Wa1T_OFF 139264
#define Wa2T_OFF 147456
#define WsT_OFF 278528
#define WT_TOTAL 282624

__device__ __forceinline__ void splitf(float v, __hip_bfloat16& h, __hip_bfloat16& l) {
    h = __float2bfloat16(v);
    l = __float2bfloat16(v - __bfloat162float(h));
}

// ---------- dense GEMM tile (block tile 128x64, 4 waves 2x2, wave tile 64x32) ----------
// AMODE 0: A as hi/lo bf16 (rows < Mpad valid memory); AMODE 1: A fp32 row-guarded, in-reg split.
// Epilogue: +bias, relu, then *rsqrt(cursor[row]+1) if DIS (pre-scale for next SpMM).

template<int AMODE, bool BIAS, bool RELU, bool DIS, bool SPLITOUT, bool NT>
__device__ void dev_gemm(float* smem, int bx, int byy,
        const __hip_bfloat16* __restrict__ Ahi, const __hip_bfloat16* __restrict__ Alo,
        const float* __restrict__ Af,
        const __hip_bfloat16* __restrict__ Bthi, const __hip_bfloat16* __restrict__ Btlo,
        const float* __restrict__ bias, const int* __restrict__ cursor,
        float* __restrict__ Cf, __hip_bfloat16* __restrict__ Chi, __hip_bfloat16* __restrict__ Clo,
        int M, int K, int ldc) {
    int tid = threadIdx.x;
    int w = tid >> 6, lane = tid & 63;
    int wr = w >> 1, wc = w & 1;
    int m0 = byy * 128, n0 = bx * 64;
    int lrow = lane & 15, lk = (lane >> 4) * 8;

    int arow[4];
    size_t aoff[4];
#pragma unroll
    for (int mi = 0; mi < 4; ++mi) {
        arow[mi] = m0 + wr * 64 + mi * 16 + lrow;
        aoff[mi] = (size_t)arow[mi] * K + lk;
    }
    size_t boff[2];
#pragma unroll
    for (int nj = 0; nj < 2; ++nj)
        boff[nj] = (size_t)(n0 + wc * 32 + nj * 16 + lrow) * K + lk;

    f32x4 acc[4][2] = {};

    for (int k0 = 0; k0 < K; k0 += 32) {
        bf16x8 bh[2], bl[2], ah[4], al[4];
#pragma unroll
        for (int nj = 0; nj < 2; ++nj) {
            bh[nj] = *(const bf16x8*)(Bthi + boff[nj] + k0);
            bl[nj] = *(const bf16x8*)(Btlo + boff[nj] + k0);
        }
        if constexpr (AMODE == 0) {
#pragma unroll
            for (int mi = 0; mi < 4; ++mi) {
                ah[mi] = *(const bf16x8*)(Ahi + aoff[mi] + k0);
                al[mi] = *(const bf16x8*)(Alo + aoff[mi] + k0);
            }
        } else {
#pragma unroll
            for (int mi = 0; mi < 4; ++mi) {
                float4 f0 = make_float4(0.f, 0.f, 0.f, 0.f), f1 = f0;
                if (arow[mi] < M) {
                    f0 = *(const float4*)(Af + aoff[mi] + k0);
                    f1 = *(const float4*)(Af + aoff[mi] + k0 + 4);
                }
                float ff[8] = {f0.x, f0.y, f0.z, f0.w, f1.x, f1.y, f1.z, f1.w};
                __attribute__((aligned(16))) __hip_bfloat16 hb[8], lb[8];
#pragma unroll
                for (int t = 0; t < 8; ++t) splitf(ff[t], hb[t], lb[t]);
                ah[mi] = *(const bf16x8*)hb;
                al[mi] = *(const bf16x8*)lb;
            }
        }
#pragma unroll
        for (int mi = 0; mi < 4; ++mi)
#pragma unroll
            for (int nj = 0; nj < 2; ++nj) {
                acc[mi][nj] = __builtin_amdgcn_mfma_f32_16x16x32_bf16(ah[mi], bh[nj], acc[mi][nj], 0, 0, 0);
                acc[mi][nj] = __builtin_amdgcn_mfma_f32_16x16x32_bf16(ah[mi], bl[nj], acc[mi][nj], 0, 0, 0);
                acc[mi][nj] = __builtin_amdgcn_mfma_f32_16x16x32_bf16(al[mi], bh[nj], acc[mi][nj], 0, 0, 0);
            }
    }

    // stage to LDS, stride 68 (2-way banks on stage and read — free)
    int r0 = (lane >> 4) * 4;
#pragma unroll
    for (int mi = 0; mi < 4; ++mi)
#pragma unroll
        for (int nj = 0; nj < 2; ++nj) {
            int cl = wc * 32 + nj * 16 + lrow;
#pragma unroll
            for (int r = 0; r < 4; ++r) {
                int rl = wr * 64 + mi * 16 + r0 + r;
                smem[rl * 68 + cl] = acc[mi][nj][r];
            }
        }
    __syncthreads();

#pragma unroll
    for (int it = 0; it < 8; ++it) {
        int rl = it * 16 + (tid >> 4);
        int c4 = tid & 15;
        int row = m0 + rl;
        if (row < M) {
            int col = n0 + c4 * 4;
            float4 v = *(const float4*)&smem[rl * 68 + c4 * 4];
            if (BIAS) {
                float4 b = *(const float4*)&bias[col];
                v.x += b.x; v.y += b.y; v.z += b.z; v.w += b.w;
            }
            if (RELU) {
                v.x = fmaxf(v.x, 0.f); v.y = fmaxf(v.y, 0.f);
                v.z = fmaxf(v.z, 0.f); v.w = fmaxf(v.w, 0.f);
            }
            if (DIS) {
                float di = rsqrtf((float)(cursor[row] + 1));
                v.x *= di; v.y *= di; v.z *= di; v.w *= di;
            }
            if constexpr (SPLITOUT) {
                float vv[4] = {v.x, v.y, v.z, v.w};
                __attribute__((aligned(8))) __hip_bfloat16 hs[4], ls[4];
#pragma unroll
                for (int k = 0; k < 4; ++k) splitf(vv[k], hs[k], ls[k]);
                *(bf16x4*)&Chi[(size_t)row * ldc + col] = *(bf16x4*)hs;
                *(bf16x4*)&Clo[(size_t)row * ldc + col] = *(bf16x4*)ls;
            } else if constexpr (NT) {
                __builtin_nontemporal_store(*(const f32x4*)&v, (f32x4*)&Cf[(size_t)row * ldc + col]);
            } else {
                *(float4*)&Cf[(size_t)row * ldc + col] = v;
            }
        }
    }
    __syncthreads();
}

// ---------- sst 128x128 tile, upper triangle; mirror written DIRECT from acc (float4, full lines) ----------

__device__ void dev_sst(float* smem, int bi, int bj,
                        const __hip_bfloat16* __restrict__ Shi, const __hip_bfloat16* __restrict__ Slo,
                        float* __restrict__ C, int M) {
    int tid = threadIdx.x;
    int w = tid >> 6, lane = tid & 63;
    int wr = w >> 1, wc = w & 1;
    int i0 = bi * 128 + wr * 64;
    int j0 = bj * 128 + wc * 64;
    int lrow = lane & 15, lk = (lane >> 4) * 8;

    f32x4 acc[4][4] = {};
#pragma unroll
    for (int ks = 0; ks < 2; ++ks) {
        bf16x8 ah[4], al[4], bh[4], bl[4];
#pragma unroll
        for (int mi = 0; mi < 4; ++mi) {
            size_t off = (size_t)(i0 + mi * 16 + lrow) * 64 + ks * 32 + lk;
            ah[mi] = *(const bf16x8*)(Shi + off);
            al[mi] = *(const bf16x8*)(Slo + off);
        }
#pragma unroll
        for (int nj = 0; nj < 4; ++nj) {
            size_t off = (size_t)(j0 + nj * 16 + lrow) * 64 + ks * 32 + lk;
            bh[nj] = *(const bf16x8*)(Shi + off);
            bl[nj] = *(const bf16x8*)(Slo + off);
        }
#pragma unroll
        for (int mi = 0; mi < 4; ++mi)
#pragma unroll
            for (int nj = 0; nj < 4; ++nj) {
                acc[mi][nj] = __builtin_amdgcn_mfma_f32_16x16x32_bf16(ah[mi], bh[nj], acc[mi][nj], 0, 0, 0);
                acc[mi][nj] = __builtin_amdgcn_mfma_f32_16x16x32_bf16(ah[mi], bl[nj], acc[mi][nj], 0, 0, 0);
                acc[mi][nj] = __builtin_amdgcn_mfma_f32_16x16x32_bf16(al[mi], bh[nj], acc[mi][nj], 0, 0, 0);
            }
    }

    int r0 = (lane >> 4) * 4;

    // mirror write (C symmetric): acc[mi][nj] = 4 consecutive rows of one col
    // -> 4 consecutive cols of the mirrored tile -> direct float4, 16 rows x 64B lines per instr
    if (bi != bj) {
#pragma unroll
        for (int mi = 0; mi < 4; ++mi)
#pragma unroll
            for (int nj = 0; nj < 4; ++nj) {
                int orow = j0 + nj * 16 + lrow;       // mirrored out row
                int ocol = i0 + mi * 16 + r0;         // mirrored out col (x4)
                if (orow < M && ocol < M) {
                    f32x4 v = acc[mi][nj];
                    __builtin_nontemporal_store(v, (f32x4*)&C[(size_t)orow * M + ocol]);
                }
            }
    }

    // normal write via LDS transpose, two 64-col passes (34KB)
#pragma unroll
    for (int p = 0; p < 2; ++p) {
        if (wc == p) {
#pragma unroll
            for (int mi = 0; mi < 4; ++mi)
#pragma unroll
                for (int nj = 0; nj < 4; ++nj) {
                    int cl = nj * 16 + lrow;
#pragma unroll
                    for (int r = 0; r < 4; ++r) {
                        int rl = wr * 64 + mi * 16 + r0 + r;
                        smem[rl * 68 + cl] = acc[mi][nj][r];
                    }
                }
        }
        __syncthreads();
#pragma unroll
        for (int it = 0; it < 8; ++it) {
            int rl = it * 16 + (tid >> 4);
            int c4 = tid & 15;
            int row = bi * 128 + rl;
            int col = bj * 128 + p * 64 + c4 * 4;
            if (row < M && col < M) {
                float4 v = *(const float4*)&smem[rl * 68 + c4 * 4];
                __builtin_nontemporal_store(*(const f32x4*)&v, (f32x4*)&C[(size_t)row * M + col]);
            }
        }
        __syncthreads();
    }
}

// ---------- kernels ----------

// prep: weight transpose+split + edge fill (cursor pre-zeroed by memset)
__global__ __launch_bounds__(256) void k_prep(const float* __restrict__ W1, const float* __restrict__ W2,
                                              const float* __restrict__ Wa1, const float* __restrict__ Wa2,
                                              const float* __restrict__ Ws,
                                              __hip_bfloat16* __restrict__ hi, __hip_bfloat16* __restrict__ lo,
                                              const int* __restrict__ ei, int* cursor,
                                              int* __restrict__ colPad, int E) {
    int gtid = blockIdx.x * 256 + threadIdx.x;
    int gsz = gridDim.x * 256;
    for (int e = gtid; e < E; e += gsz) {
        int s = ei[e], r = ei[E + e];
        int slot = atomicAdd(&cursor[r], 1);
        if (slot < DEGPAD) colPad[(size_t)r * DEGPAD + slot] = s;
    }
    for (int idx = gtid; idx < WT_TOTAL; idx += gsz) {
        const float* src; int base, shK, Nc;
        if (idx < W2T_OFF)       { src = W1;  base = W1T_OFF;  shK = 10; Nc = 128; }
        else if (idx < Wa1T_OFF) { src = W2;  base = W2T_OFF;  shK = 7;  Nc = 64; }
        else if (idx < Wa2T_OFF) { src = Wa1; base = Wa1T_OFF; shK = 6;  Nc = 128; }
        else if (idx < WsT_OFF)  { src = Wa2; base = Wa2T_OFF; shK = 7;  Nc = 1024; }
        else                     { src = Ws;  base = WsT_OFF;  shK = 6;  Nc = 64; }
        int local = idx - base;
        int nn = local >> shK;
        int k = local & ((1 << shK) - 1);
        splitf(src[(size_t)k * Nc + nn], hi[idx], lo[idx]);
    }
}

// G1: t128 = dis ⊙ (x @ W1)  (fp32 A, in-reg split; cursor final -> DIS epilogue)
__global__ __launch_bounds__(256) void k_g1(const float* __restrict__ x,
                                            const __hip_bfloat16* __restrict__ Whi,
                                            const __hip_bfloat16* __restrict__ Wlo,
                                            const int* __restrict__ cursor,
                                            float* __restrict__ t128, int M) {
    __shared__ float smem[128 * 68];
    int t = blockIdx.x;
    dev_gemm<1, false, false, true, false, false>(smem, t & 1, t >> 1,
        nullptr, nullptr, x, Whi + W1T_OFF, Wlo + W1T_OFF, nullptr, cursor,
        t128, nullptr, nullptr, M, 1024, 128);
}

// SpMM, 8-deep ILP gather (input pre-scaled by producer).
// OMODE 0: fp32; 1: split bf16; 2: fp32 + prescaled copy.
template<int F, bool BIAS, bool RELU, int OMODE>
__global__ __launch_bounds__(256) void k_spmm(const float* __restrict__ Hin,
                                              const int* __restrict__ colPad,
                                              const int* __restrict__ cursor,
                                              const float* __restrict__ bias,
                                              float* __restrict__ out, float* __restrict__ out2,
                                              __hip_bfloat16* __restrict__ ohi,
                                              __hip_bfloat16* __restrict__ olo, int n) {
    constexpr int JW = F / 64;
    int i = (blockIdx.x * 256 + threadIdx.x) >> 6;
    int lane = threadIdx.x & 63;
    if (i >= n) return;
    int d = cursor[i];
    float di = rsqrtf((float)(d + 1));
    if (d > DEGPAD) d = DEGPAD;
    const int* cp = colPad + (size_t)i * DEGPAD;
    float acc[JW];
    const float* self = Hin + (size_t)i * F;
#pragma unroll
    for (int j = 0; j < JW; ++j) acc[j] = self[lane + 64 * j];

    int p = 0;
    for (; p + 8 <= d; p += 8) {
        int4 ca = *(const int4*)(cp + p);
        int4 cb = *(const int4*)(cp + p + 4);
        int cc[8] = {ca.x, ca.y, ca.z, ca.w, cb.x, cb.y, cb.z, cb.w};
        float vals[8][JW];
#pragma unroll
        for (int q = 0; q < 8; ++q) {
            const float* row = Hin + (size_t)cc[q] * F;
#pragma unroll
            for (int j = 0; j < JW; ++j) vals[q][j] = row[lane + 64 * j];
        }
#pragma unroll
        for (int q = 0; q < 8; ++q)
#pragma unroll
            for (int j = 0; j < JW; ++j) acc[j] += vals[q][j];
    }
    for (; p + 4 <= d; p += 4) {
        int4 ca = *(const int4*)(cp + p);
        int cc[4] = {ca.x, ca.y, ca.z, ca.w};
        float vals[4][JW];
#pragma unroll
        for (int q = 0; q < 4; ++q) {
            const float* row = Hin + (size_t)cc[q] * F;
#pragma unroll
            for (int j = 0; j < JW; ++j) vals[q][j] = row[lane + 64 * j];
        }
#pragma unroll
        for (int q = 0; q < 4; ++q)
#pragma unroll
            for (int j = 0; j < JW; ++j) acc[j] += vals[q][j];
    }
    for (; p < d; ++p) {
        const float* row = Hin + (size_t)cp[p] * F;
#pragma unroll
        for (int j = 0; j < JW; ++j) acc[j] += row[lane + 64 * j];
    }

#pragma unroll
    for (int j = 0; j < JW; ++j) {
        float r = acc[j] * di;
        if (BIAS) r += bias[lane + 64 * j];
        if (RELU) r = fmaxf(r, 0.f);
        size_t idx = (size_t)i * F + lane + 64 * j;
        if constexpr (OMODE == 1) {
            __hip_bfloat16 h, l;
            splitf(r, h, l);
            ohi[idx] = h; olo[idx] = l;
        } else {
            out[idx] = r;
            if constexpr (OMODE == 2) out2[idx] = r * di;
        }
    }
}

// G2: t64 = dis ⊙ (H @ W2)
__global__ __launch_bounds__(256) void k_g2(const __hip_bfloat16* __restrict__ Hhi,
                                            const __hip_bfloat16* __restrict__ Hlo,
                                            const __hip_bfloat16* __restrict__ Whi,
                                            const __hip_bfloat16* __restrict__ Wlo,
                                            const int* __restrict__ cursor,
                                            float* __restrict__ t64, int M) {
    __shared__ float smem[128 * 68];
    dev_gemm<0, false, false, true, false, false>(smem, 0, blockIdx.x,
        Hhi, Hlo, nullptr, Whi + W2T_OFF, Wlo + W2T_OFF, nullptr, cursor,
        t64, nullptr, nullptr, M, 128, 64);
}

// G3 (t128 = dis ⊙ relu(AZ@Wa1+ba1)) + G4 (S = relu(AZ@Ws+bs) -> split)
__global__ __launch_bounds__(256) void k_g34(const __hip_bfloat16* __restrict__ AZhi,
                                             const __hip_bfloat16* __restrict__ AZlo,
                                             const __hip_bfloat16* __restrict__ Whi,
                                             const __hip_bfloat16* __restrict__ Wlo,
                                             const float* __restrict__ ba1, const float* __restrict__ bs,
                                             const int* __restrict__ cursor,
                                             float* __restrict__ t128,
                                             __hip_bfloat16* __restrict__ Shi, __hip_bfloat16* __restrict__ Slo,
                                             int M, int Mpad) {
    __shared__ float smem[128 * 68];
    int nt2 = (Mpad / 128) * 2;
    int t = blockIdx.x;
    if (t < nt2)
        dev_gemm<0, true, true, true, false, false>(smem, t & 1, t >> 1,
            AZhi, AZlo, nullptr, Whi + Wa1T_OFF, Wlo + Wa1T_OFF, ba1, cursor,
            t128, nullptr, nullptr, M, 64, 128);
    else
        dev_gemm<0, true, true, false, true, false>(smem, 0, t - nt2,
            AZhi, AZlo, nullptr, Whi + WsT_OFF, Wlo + WsT_OFF, bs, nullptr,
            nullptr, Shi, Slo, M, 64, 64);
}

// tail: G5 (attr, NT) + sst upper-triangle
__global__ __launch_bounds__(256) void k_tail(const __hip_bfloat16* __restrict__ AAhi,
                                              const __hip_bfloat16* __restrict__ AAlo,
                                              const __hip_bfloat16* __restrict__ Whi,
                                              const __hip_bfloat16* __restrict__ Wlo,
                                              const float* __restrict__ ba2,
                                              const __hip_bfloat16* __restrict__ Shi,
                                              const __hip_bfloat16* __restrict__ Slo,
                                              float* __restrict__ attr, float* __restrict__ st,
                                              int M, int Mpad) {
    __shared__ float smem[128 * 68];
    int nt = Mpad / 128;
    int nG5 = 16 * nt;
    int t = blockIdx.x;
    if (t < nG5) {
        dev_gemm<0, true, true, false, false, true>(smem, t & 15, t >> 4,
            AAhi, AAlo, nullptr, Whi + Wa2T_OFF, Wlo + Wa2T_OFF, ba2, nullptr,
            attr, nullptr, nullptr, M, 128, 1024);
    } else {
        int tt = t - nG5;
        int bi = 0;
        while (tt >= nt - bi) { tt -= nt - bi; bi++; }
        dev_sst(smem, bi, bi + tt, Shi, Slo, st, M);
    }
}

// ---------- launch ----------

extern "C" void kernel_launch(void* const* d_in, const int* in_sizes, int n_in,
                              void* d_out, int out_size, void* d_ws, size_t ws_size,
                              hipStream_t stream) {
    const float* x   = (const float*)d_in[0];
    const int*   ei  = (const int*)d_in[1];
    const float* W1  = (const float*)d_in[2];
    const float* b1  = (const float*)d_in[3];
    const float* W2  = (const float*)d_in[4];
    const float* b2  = (const float*)d_in[5];
    const float* Wa1 = (const float*)d_in[6];
    const float* ba1 = (const float*)d_in[7];
    const float* Wa2 = (const float*)d_in[8];
    const float* ba2 = (const float*)d_in[9];
    const float* Ws  = (const float*)d_in[10];
    const float* bs  = (const float*)d_in[11];

    int N = in_sizes[0] / IN_DIM;
    int E = in_sizes[1] / 2;
    int Mpad = ((N + 127) / 128) * 128;
    int nt = Mpad / 128;

    float* out  = (float*)d_out;
    float* attr = out;
    float* st   = out + (size_t)N * IN_DIM;
    float* zout = st + (size_t)N * N;

    char* basep = (char*)d_ws;
    size_t off = 0;
    auto alloc = [&](size_t bytes) -> void* {
        void* p = basep + off;
        off = (off + bytes + 255) & ~(size_t)255;
        return p;
    };
    int*   colPad = (int*)alloc((size_t)N * DEGPAD * 4);
    int*   cursor = (int*)alloc((size_t)N * 4);
    __hip_bfloat16* Whi = (__hip_bfloat16*)alloc((size_t)WT_TOTAL * 2);
    __hip_bfloat16* Wlo = (__hip_bfloat16*)alloc((size_t)WT_TOTAL * 2);
    float* t128 = (float*)alloc((size_t)N * 128 * 4);
    float* t64  = (float*)alloc((size_t)N * 64 * 4);
    float* zp   = (float*)alloc((size_t)N * 64 * 4);
    __hip_bfloat16* Hhi  = (__hip_bfloat16*)alloc((size_t)Mpad * 128 * 2);
    __hip_bfloat16* Hlo  = (__hip_bfloat16*)alloc((size_t)Mpad * 128 * 2);
    __hip_bfloat16* AZhi = (__hip_bfloat16*)alloc((size_t)Mpad * 64 * 2);
    __hip_bfloat16* AZlo = (__hip_bfloat16*)alloc((size_t)Mpad * 64 * 2);
    __hip_bfloat16* AAhi = (__hip_bfloat16*)alloc((size_t)Mpad * 128 * 2);
    __hip_bfloat16* AAlo = (__hip_bfloat16*)alloc((size_t)Mpad * 128 * 2);
    __hip_bfloat16* Shi  = (__hip_bfloat16*)alloc((size_t)Mpad * 64 * 2);
    __hip_bfloat16* Slo  = (__hip_bfloat16*)alloc((size_t)Mpad * 64 * 2);

    dim3 b256(256);
    int spmm_grid = (N * 64 + 255) / 256;

    // 0. zero cursor (async memset node in the graph)
    hipMemsetAsync(cursor, 0, (size_t)N * 4, stream);
    // 1. prep: weight split + edge fill
    k_prep<<<dim3(1280), b256, 0, stream>>>(W1, W2, Wa1, Wa2, Ws, Whi, Wlo, ei, cursor, colPad, E);
    // 2. G1: t128 = dis ⊙ (x @ W1)
    k_g1<<<dim3(2 * nt), b256, 0, stream>>>(x, Whi, Wlo, cursor, t128, N);
    // 3. spmm1 (prescaled): H = relu(dis ⊙ Σ + b1) -> split
    k_spmm<128, true, true, 1><<<dim3(spmm_grid), b256, 0, stream>>>(
        t128, colPad, cursor, b1, nullptr, nullptr, Hhi, Hlo, N);
    // 4. G2: t64 = dis ⊙ (H @ W2)
    k_g2<<<dim3(nt), b256, 0, stream>>>(Hhi, Hlo, Whi, Wlo, cursor, t64, N);
    // 5. spmm2 (prescaled): z -> zout (fp32) and zp = dis ⊙ z
    k_spmm<64, true, true, 2><<<dim3(spmm_grid), b256, 0, stream>>>(
        t64, colPad, cursor, b2, zout, zp, nullptr, nullptr, N);
    // 6. spmm3 (prescaled): AZ = prop(zp) -> split
    k_spmm<64, false, false, 1><<<dim3(spmm_grid), b256, 0, stream>>>(
        zp, colPad, cursor, nullptr, nullptr, nullptr, AZhi, AZlo, N);
    // 7. G3 + G4
    k_g34<<<dim3(3 * nt), b256, 0, stream>>>(AZhi, AZlo, Whi, Wlo, ba1, bs, cursor, t128, Shi, Slo, N, Mpad);
    // 8. spmm4 (prescaled): AA = prop(t128) -> split
    k_spmm<128, false, false, 1><<<dim3(spmm_grid), b256, 0, stream>>>(
        t128, colPad, cursor, nullptr, nullptr, nullptr, AAhi, AAlo, N);
    // 9. tail: G5 (attr) + sst upper-triangle (struct)
    k_tail<<<dim3(16 * nt + nt * (nt + 1) / 2), b256, 0, stream>>>(
        AAhi, AAlo, Whi, Wlo, ba2, Shi, Slo, attr, st, N, Mpad);
}